// Round 6
// baseline (594.983 us; speedup 1.0000x reference)
//
#include <hip/hip_runtime.h>
#include <math.h>

// Problem constants (fixed by the reference).
#define N_ROWS 16384
#define D_INN  360
#define KP1    384      // D_INN padded to multiple of 64
#define HID    512
#define M_SLOTS 2048

typedef __attribute__((ext_vector_type(8))) short short8v;
typedef __attribute__((ext_vector_type(4))) float f32x4;
typedef __attribute__((address_space(1))) unsigned int as1_uint;
typedef __attribute__((address_space(3))) unsigned int as3_uint;

// ---- bf16 helpers (manual, RNE) ----
__device__ __forceinline__ unsigned short bf16_rne(float f){
  unsigned u = __float_as_uint(f);
  unsigned r = u + 0x7FFFu + ((u >> 16) & 1u);
  return (unsigned short)(r >> 16);
}
__device__ __forceinline__ float bf16_to_f32(unsigned short h){
  return __uint_as_float(((unsigned)h) << 16);
}

__device__ __forceinline__ void glds16(const void* g, void* l){
  __builtin_amdgcn_global_load_lds((const as1_uint*)g, (as3_uint*)l, 16, 0, 0);
}

// reconstruct 4 consecutive f32 from hi/lo bf16 pair arrays
__device__ __forceinline__ float4 ld4bf(const unsigned short* hi, const unsigned short* lo, size_t off){
  uint2 h = *(const uint2*)(hi + off);
  uint2 l = *(const uint2*)(lo + off);
  float4 r;
  r.x = bf16_to_f32((unsigned short)(h.x & 0xffffu)) + bf16_to_f32((unsigned short)(l.x & 0xffffu));
  r.y = bf16_to_f32((unsigned short)(h.x >> 16))     + bf16_to_f32((unsigned short)(l.x >> 16));
  r.z = bf16_to_f32((unsigned short)(h.y & 0xffffu)) + bf16_to_f32((unsigned short)(l.y & 0xffffu));
  r.w = bf16_to_f32((unsigned short)(h.y >> 16))     + bf16_to_f32((unsigned short)(l.y >> 16));
  return r;
}

// ============================ conversion kernels ============================

// split f32 -> bf16 hi + bf16 lo (residual); nelem multiple of 2048
__global__ __launch_bounds__(256) void cvt_split(const float* __restrict__ src,
                                                 unsigned short* __restrict__ hi,
                                                 unsigned short* __restrict__ lo,
                                                 int nelem)
{
  int idx = (blockIdx.x*256 + threadIdx.x) * 8;
  if (idx >= nelem) return;
  float4 a = *(const float4*)&src[idx];
  float4 b = *(const float4*)&src[idx+4];
  float v[8] = {a.x,a.y,a.z,a.w,b.x,b.y,b.z,b.w};
  short8v hv, lv;
#pragma unroll
  for (int e=0;e<8;++e){
    unsigned short h = bf16_rne(v[e]);
    float hf = bf16_to_f32(h);
    hv[e] = (short)h;
    lv[e] = (short)bf16_rne(v[e] - hf);
  }
  *(short8v*)&hi[idx] = hv;
  *(short8v*)&lo[idx] = lv;
}

// f32 [R][Ksrc] -> split bf16 [R][Kp] with zero padding for c >= Ksrc.
__global__ __launch_bounds__(256) void cvt_pad_split(const float* __restrict__ src,
                                                     unsigned short* __restrict__ hi,
                                                     unsigned short* __restrict__ lo,
                                                     int R, int Ksrc, int Kp)
{
  long long e0 = ((long long)blockIdx.x*256 + threadIdx.x) * 4;
  if (e0 >= (long long)R*Kp) return;
  int row = (int)(e0 / Kp), c = (int)(e0 % Kp);
  unsigned short h4[4], l4[4];
  if (c < Ksrc){
    float4 v = *(const float4*)&src[(size_t)row*Ksrc + c];
    float vv[4] = {v.x, v.y, v.z, v.w};
#pragma unroll
    for (int e=0;e<4;++e){
      unsigned short h = bf16_rne(vv[e]);
      h4[e] = h;
      l4[e] = bf16_rne(vv[e] - bf16_to_f32(h));
    }
  } else {
#pragma unroll
    for (int e=0;e<4;++e){ h4[e]=0; l4[e]=0; }
  }
  *(uint2*)&hi[(size_t)row*Kp + c] = *(uint2*)h4;
  *(uint2*)&lo[(size_t)row*Kp + c] = *(uint2*)l4;
}

// Kt[h][slot] = bf16(K[slot][h])  -- transposed bf16 copy of memory matrix
__global__ __launch_bounds__(256) void kt_kernel(const float* __restrict__ K,
                                                 unsigned short* __restrict__ Kt)
{
  __shared__ float tile[64][65];
  const int sb = blockIdx.x * 64;  // slot base
  const int hb = blockIdx.y * 64;  // h base
  const int t = threadIdx.x;
  {
    int r = t >> 2, cq = t & 3;
#pragma unroll
    for (int q=0;q<4;++q){
      float4 v = *(const float4*)&K[(size_t)(sb+r)*HID + hb + cq*16 + q*4];
      tile[r][cq*16+q*4+0]=v.x; tile[r][cq*16+q*4+1]=v.y;
      tile[r][cq*16+q*4+2]=v.z; tile[r][cq*16+q*4+3]=v.w;
    }
  }
  __syncthreads();
  {
    int hl = t >> 2, sq = t & 3;
    unsigned short w16[16];
#pragma unroll
    for (int q=0;q<16;++q) w16[q] = bf16_rne(tile[sq*16+q][hl]);
    *(uint4*)&Kt[(size_t)(hb+hl)*M_SLOTS + sb + sq*16]     = *(uint4*)&w16[0];
    *(uint4*)&Kt[(size_t)(hb+hl)*M_SLOTS + sb + sq*16 + 8] = *(uint4*)&w16[8];
  }
}

// pred[i] = bd (init before mlp3's fused atomic dot)
__global__ __launch_bounds__(256) void pred_init(float* __restrict__ pred, const float* __restrict__ bd){
  pred[blockIdx.x*256 + threadIdx.x] = bd[0];
}

// ============================ MLP GEMM (3-term split bf16 MFMA) ============================
// Optional fused pred: when predp != nullptr, accumulate row-dot with Wd via atomics.
__global__ __launch_bounds__(256) void mlp_gemm(
    const unsigned short* __restrict__ Ah_g, const unsigned short* __restrict__ Al_g,
    const unsigned short* __restrict__ Wh_g, const unsigned short* __restrict__ Wl_g,
    const float* __restrict__ bias,
    unsigned short* __restrict__ Ohi, unsigned short* __restrict__ Olo,
    int Kp, const float* __restrict__ Wd, float* __restrict__ predp)
{
  __shared__ char smem[49152];
  unsigned short* Ah = (unsigned short*)smem;            // [64][64] bf16, chunk-swizzled
  unsigned short* Al = (unsigned short*)(smem + 8192);
  unsigned short* Bh = (unsigned short*)(smem + 16384);  // [128][64]
  unsigned short* Bl = (unsigned short*)(smem + 32768);
  const int t = threadIdx.x;
  const int lane = t & 63, w = t >> 6;
  const int l15 = lane & 15, l4 = lane >> 4;
  const int rowBase = blockIdx.x * 64;
  const int colBase = blockIdx.y * 128;
  const int wr = (w >> 1) * 32;
  const int wc = (w & 1) * 64;

  f32x4 acc[2][4];
#pragma unroll
  for (int i=0;i<2;++i)
#pragma unroll
    for (int j=0;j<4;++j) acc[i][j] = (f32x4){0.f,0.f,0.f,0.f};

  const int nkt = Kp >> 6;
  for (int kt = 0; kt < nkt; ++kt){
    const int k0 = kt * 64;
#pragma unroll
    for (int p = 0; p < 2; ++p){
      int idx = p*256 + t;
      int r = idx >> 3, c = idx & 7;
      int cc = c ^ (r & 7);
      size_t go = (size_t)(rowBase + r) * Kp + (k0 + cc*8);
      glds16(Ah_g + go, (char*)Ah + idx*16);
      glds16(Al_g + go, (char*)Al + idx*16);
    }
#pragma unroll
    for (int p = 0; p < 4; ++p){
      int idx = p*256 + t;
      int r = idx >> 3, c = idx & 7;
      int cc = c ^ (r & 7);
      size_t go = (size_t)(colBase + r) * Kp + (k0 + cc*8);
      glds16(Wh_g + go, (char*)Bh + idx*16);
      glds16(Wl_g + go, (char*)Bl + idx*16);
    }
    __syncthreads();

#pragma unroll
    for (int s = 0; s < 2; ++s){
      short8v a_h[2], a_l[2], b_h[4], b_l[4];
#pragma unroll
      for (int rt = 0; rt < 2; ++rt){
        int r = wr + rt*16 + l15;
        int off = r*128 + ((s*4 + l4) ^ (r & 7))*16;
        a_h[rt] = *(const short8v*)((const char*)Ah + off);
        a_l[rt] = *(const short8v*)((const char*)Al + off);
      }
#pragma unroll
      for (int ct = 0; ct < 4; ++ct){
        int r = wc + ct*16 + l15;
        int off = r*128 + ((s*4 + l4) ^ (r & 7))*16;
        b_h[ct] = *(const short8v*)((const char*)Bh + off);
        b_l[ct] = *(const short8v*)((const char*)Bl + off);
      }
#pragma unroll
      for (int rt = 0; rt < 2; ++rt)
#pragma unroll
        for (int ct = 0; ct < 4; ++ct){
          acc[rt][ct] = __builtin_amdgcn_mfma_f32_16x16x32_bf16(a_h[rt], b_h[ct], acc[rt][ct], 0,0,0);
          acc[rt][ct] = __builtin_amdgcn_mfma_f32_16x16x32_bf16(a_h[rt], b_l[ct], acc[rt][ct], 0,0,0);
          acc[rt][ct] = __builtin_amdgcn_mfma_f32_16x16x32_bf16(a_l[rt], b_h[ct], acc[rt][ct], 0,0,0);
        }
    }
    __syncthreads();
  }

  // epilogue: bias + relu, split hi/lo, stage through LDS for coalesced writes
  float bcol[4];
#pragma unroll
  for (int ct=0; ct<4; ++ct) bcol[ct] = bias[colBase + wc + ct*16 + l15];
  unsigned short* Sout = (unsigned short*)smem;  // [64][136]
#pragma unroll
  for (int rt=0; rt<2; ++rt)
#pragma unroll
    for (int ct=0; ct<4; ++ct)
#pragma unroll
      for (int reg=0; reg<4; ++reg){
        float v = acc[rt][ct][reg] + bcol[ct];
        v = v > 0.f ? v : 0.f;
        acc[rt][ct][reg] = v;
        Sout[(wr + rt*16 + l4*4 + reg)*136 + wc + ct*16 + l15] = bf16_rne(v);
      }

  // fused pred partial (last layer only): row-dot over this block's 128 cols
  if (predp){
    float wdv[4];
#pragma unroll
    for (int ct=0; ct<4; ++ct) wdv[ct] = Wd[colBase + wc + ct*16 + l15];
#pragma unroll
    for (int rt=0; rt<2; ++rt)
#pragma unroll
      for (int reg=0; reg<4; ++reg){
        float pd = acc[rt][0][reg]*wdv[0] + acc[rt][1][reg]*wdv[1]
                 + acc[rt][2][reg]*wdv[2] + acc[rt][3][reg]*wdv[3];
#pragma unroll
        for (int d=1; d<16; d<<=1) pd += __shfl_xor(pd, d);
        if (l15 == 0)
          atomicAdd(&predp[rowBase + wr + rt*16 + l4*4 + reg], pd);
      }
  }

  __syncthreads();
#pragma unroll
  for (int p = 0; p < 4; ++p){
    int row = (t >> 4) + p*16;
    int c8 = (t & 15) * 8;
    uint4 v = *(uint4*)&Sout[row*136 + c8];
    *(uint4*)&Ohi[(size_t)(rowBase+row)*HID + colBase + c8] = v;
  }
  __syncthreads();
#pragma unroll
  for (int rt=0; rt<2; ++rt)
#pragma unroll
    for (int ct=0; ct<4; ++ct)
#pragma unroll
      for (int reg=0; reg<4; ++reg){
        float v = acc[rt][ct][reg];
        unsigned short h = bf16_rne(v);
        Sout[(wr + rt*16 + l4*4 + reg)*136 + wc + ct*16 + l15] = bf16_rne(v - bf16_to_f32(h));
      }
  __syncthreads();
#pragma unroll
  for (int p = 0; p < 4; ++p){
    int row = (t >> 4) + p*16;
    int c8 = (t & 15) * 8;
    uint4 v = *(uint4*)&Sout[row*136 + c8];
    *(uint4*)&Olo[(size_t)(rowBase+row)*HID + colBase + c8] = v;
  }
}

// ============================ S GEMM + stats ============================
// BM=128 x BN=128, BK=64; hi operands via LDS (32KB), lo operands direct
// global->VGPR per-lane 16B loads (L2-served). 96 MFMA : 8 glds per wave/kt.
__global__ __launch_bounds__(256) void sgemm_stats(
    const unsigned short* __restrict__ Qhi, const unsigned short* __restrict__ Qlo,
    const unsigned short* __restrict__ Khi, const unsigned short* __restrict__ Klo,
    unsigned short* __restrict__ Sb,
    float* __restrict__ pmax, int* __restrict__ pcol,
    float* __restrict__ psum, float* __restrict__ pnmax, float* __restrict__ pnsum,
    float* __restrict__ pcolmax)
{
  __shared__ char smem[36864];
  unsigned short* Ah = (unsigned short*)smem;            // [128][64] hi, chunk-swizzled
  unsigned short* Bh = (unsigned short*)(smem + 16384);  // [128][64] hi
  const int t = threadIdx.x;
  const int lane = t & 63, w = t >> 6;
  const int l15 = lane & 15, l4 = lane >> 4;
  const int cb = blockIdx.x;      // 0..15  col block
  const int rb = blockIdx.y;      // 0..127 row block
  const int rowBase = rb * 128;
  const int colBase = cb * 128;
  const int wr = (w >> 1) * 64;
  const int wc = (w & 1) * 64;

  f32x4 acc[4][4];
#pragma unroll
  for (int i=0;i<4;++i)
#pragma unroll
    for (int j=0;j<4;++j) acc[i][j] = (f32x4){0.f,0.f,0.f,0.f};

  for (int kt = 0; kt < 8; ++kt){
    const int k0 = kt * 64;
#pragma unroll
    for (int p = 0; p < 4; ++p){
      int idx = p*256 + t;
      int r = idx >> 3, c = idx & 7;
      int cc = c ^ (r & 7);
      glds16(Qhi + (size_t)(rowBase + r) * HID + (k0 + cc*8), (char*)Ah + idx*16);
      glds16(Khi + (size_t)(colBase + r) * HID + (k0 + cc*8), (char*)Bh + idx*16);
    }
    __syncthreads();

#pragma unroll
    for (int s = 0; s < 2; ++s){
      short8v a_h[4], a_l[4], b_h[4], b_l[4];
#pragma unroll
      for (int rt = 0; rt < 4; ++rt){
        int r = wr + rt*16 + l15;
        a_h[rt] = *(const short8v*)((const char*)Ah + r*128 + ((s*4 + l4) ^ (r & 7))*16);
        a_l[rt] = *(const short8v*)&Qlo[(size_t)(rowBase + r)*HID + k0 + s*32 + l4*8];
      }
#pragma unroll
      for (int ct = 0; ct < 4; ++ct){
        int r = wc + ct*16 + l15;
        b_h[ct] = *(const short8v*)((const char*)Bh + r*128 + ((s*4 + l4) ^ (r & 7))*16);
        b_l[ct] = *(const short8v*)&Klo[(size_t)(colBase + r)*HID + k0 + s*32 + l4*8];
      }
#pragma unroll
      for (int rt = 0; rt < 4; ++rt)
#pragma unroll
        for (int ct = 0; ct < 4; ++ct){
          acc[rt][ct] = __builtin_amdgcn_mfma_f32_16x16x32_bf16(a_h[rt], b_h[ct], acc[rt][ct], 0,0,0);
          acc[rt][ct] = __builtin_amdgcn_mfma_f32_16x16x32_bf16(a_h[rt], b_l[ct], acc[rt][ct], 0,0,0);
          acc[rt][ct] = __builtin_amdgcn_mfma_f32_16x16x32_bf16(a_l[rt], b_h[ct], acc[rt][ct], 0,0,0);
        }
    }
    __syncthreads();
  }

  // ---- row stats (per wave over its 64-col half) ----
#pragma unroll
  for (int rt = 0; rt < 4; ++rt){
#pragma unroll
    for (int reg = 0; reg < 4; ++reg){
      float v0 = acc[rt][0][reg], v1 = acc[rt][1][reg];
      float v2 = acc[rt][2][reg], v3 = acc[rt][3][reg];
      float bvv = v0; int bcc = colBase + wc + l15;
      if (v1 > bvv){ bvv = v1; bcc = colBase + wc + 16 + l15; }
      if (v2 > bvv){ bvv = v2; bcc = colBase + wc + 32 + l15; }
      if (v3 > bvv){ bvv = v3; bcc = colBase + wc + 48 + l15; }
      float mnv = fminf(fminf(v0,v1), fminf(v2,v3));
#pragma unroll
      for (int d = 1; d < 16; d <<= 1){
        float ov = __shfl_xor(bvv, d);
        int   oc = __shfl_xor(bcc, d);
        float om = __shfl_xor(mnv, d);
        if (ov > bvv || (ov == bvv && oc < bcc)){ bvv = ov; bcc = oc; }
        mnv = fminf(mnv, om);
      }
      float sp = __expf(v0-bvv)+__expf(v1-bvv)+__expf(v2-bvv)+__expf(v3-bvv);
      float sn = __expf(mnv-v0)+__expf(mnv-v1)+__expf(mnv-v2)+__expf(mnv-v3);
#pragma unroll
      for (int d = 1; d < 16; d <<= 1){ sp += __shfl_xor(sp,d); sn += __shfl_xor(sn,d); }
      if (l15 == 0){
        int row = rowBase + wr + rt*16 + l4*4 + reg;
        size_t pi = (size_t)row*32 + cb*2 + (w & 1);
        pmax[pi] = bvv; pcol[pi] = bcc; psum[pi] = sp;
        pnmax[pi] = -mnv; pnsum[pi] = sn;
      }
    }
  }

  // ---- per-column tile max (over this wave's 64 rows) ----
#pragma unroll
  for (int ct = 0; ct < 4; ++ct){
    float cm = -1e30f;
#pragma unroll
    for (int rt=0; rt<4; ++rt)
#pragma unroll
      for (int reg=0; reg<4; ++reg) cm = fmaxf(cm, acc[rt][ct][reg]);
    cm = fmaxf(cm, __shfl_xor(cm, 16));
    cm = fmaxf(cm, __shfl_xor(cm, 32));
    if (l4 == 0)
      pcolmax[(size_t)(rb*2 + (w>>1))*M_SLOTS + colBase + wc + ct*16 + l15] = cm;
  }

  // ---- S bf16 write (staged through LDS for coalescing) ----
  __syncthreads();
  unsigned short* Sout = (unsigned short*)smem;  // [128][136] = 34816 B
#pragma unroll
  for (int rt=0; rt<4; ++rt)
#pragma unroll
    for (int ct=0; ct<4; ++ct)
#pragma unroll
      for (int reg=0; reg<4; ++reg)
        Sout[(wr + rt*16 + l4*4 + reg)*136 + wc + ct*16 + l15] = bf16_rne(acc[rt][ct][reg]);
  __syncthreads();
#pragma unroll
  for (int p = 0; p < 8; ++p){
    int row = (t >> 4) + p*16;
    int c8 = (t & 15) * 8;
    uint4 v = *(uint4*)&Sout[row*136 + c8];
    *(uint4*)&Sb[(size_t)(rowBase+row)*M_SLOTS + colBase + c8] = v;
  }
}

__global__ __launch_bounds__(256) void merge_rows(
    const float* __restrict__ pmax, const int* __restrict__ pcol,
    const float* __restrict__ psum, const float* __restrict__ pnmax,
    const float* __restrict__ pnsum,
    float* __restrict__ rowm, float* __restrict__ rsp,
    float* __restrict__ rmn, float* __restrict__ rsn, int* __restrict__ gidx,
    int* __restrict__ cnt)
{
  int row = blockIdx.x*256 + threadIdx.x;
  const size_t base = (size_t)row*32;
  float m = -1e30f; int g = 0;
  for (int i=0;i<32;++i){
    float v = pmax[base+i];
    if (v > m){ m = v; g = pcol[base+i]; }
  }
  float s = 0.f;
  for (int i=0;i<32;++i) s += psum[base+i] * __expf(pmax[base+i]-m);
  float mn = -1e30f;
  for (int i=0;i<32;++i) mn = fmaxf(mn, pnmax[base+i]);
  float sn = 0.f;
  for (int i=0;i<32;++i) sn += pnsum[base+i] * __expf(pnmax[base+i]-mn);
  rowm[row]=m; gidx[row]=g; rsp[row]=1.f/s; rmn[row]=mn; rsn[row]=1.f/sn;
  atomicAdd(&cnt[g], 1);   // fused csr_count
}

__global__ __launch_bounds__(256) void merge_cols(const float* __restrict__ pcolmax,
                                                  float* __restrict__ colmax)
{
  int c = blockIdx.x*256 + threadIdx.x;
  float m = -1e30f;
  for (int r=0;r<256;++r) m = fmaxf(m, pcolmax[(size_t)r*M_SLOTS + c]);
  colmax[c] = m;
}

// ============================ PV (S read once) ============================
#define PV_RB 32
#define PV_HB 256
__global__ __launch_bounds__(256, 3) void pv2(
    const unsigned short* __restrict__ Sb, const unsigned short* __restrict__ Kt,
    const float* __restrict__ rowm, const float* __restrict__ rsp,
    const float* __restrict__ rmn, const float* __restrict__ rsn,
    const unsigned short* __restrict__ Qhi, const unsigned short* __restrict__ Qlo,
    float* __restrict__ outP, float* __restrict__ outN)
{
  __shared__ char smem[40960];
  unsigned short* Ktile = (unsigned short*)smem;          // [256 h][64 slots], chunk-swizzled, 32KB
  unsigned short* Wp = (unsigned short*)(smem + 32768);   // frag-ordered weights, 4KB
  unsigned short* Wn = (unsigned short*)(smem + 36864);   // 4KB
  const int t = threadIdx.x, lane = t & 63, w = t >> 6;
  const int l15 = lane & 15, l4 = lane >> 4;
  const int rowBase = blockIdx.y * PV_RB;
  const int hBase = blockIdx.x * PV_HB;
  const int hw = w * 64;
  const int rS = t >> 3;
  const int c8 = t & 7;
  const float mp = rowm[rowBase + rS], mn = rmn[rowBase + rS];
  const int rtw = rS >> 4;
  const int sw = c8 >> 2, l4w = c8 & 3;
  const int gw = (rtw*2 + sw)*4 + l4w;
  const int chw = gw*16 + ((rS & 15) ^ (gw & 7));

  f32x4 accP[2][4], accN[2][4];
#pragma unroll
  for (int i=0;i<2;++i)
#pragma unroll
    for (int j=0;j<4;++j){ accP[i][j]=(f32x4){0.f,0.f,0.f,0.f}; accN[i][j]=(f32x4){0.f,0.f,0.f,0.f}; }

  for (int kt = 0; kt < 32; ++kt){
    const int k0 = kt*64;
#pragma unroll
    for (int p=0;p<8;++p){
      int idx = p*256 + t;
      int r = idx >> 3, c = idx & 7;
      int cc = c ^ (r & 7);
      glds16(Kt + (size_t)(hBase + r)*M_SLOTS + k0 + cc*8, (char*)Ktile + idx*16);
    }
    short8v sv = *(const short8v*)&Sb[(size_t)(rowBase + rS)*M_SLOTS + k0 + c8*8];
    short8v wp, wn;
#pragma unroll
    for (int e=0;e<8;++e){
      float sval = bf16_to_f32((unsigned short)sv[e]);
      wp[e] = (short)bf16_rne(__expf(sval - mp));
      wn[e] = (short)bf16_rne(__expf(-sval - mn));
    }
    *(short8v*)(Wp + chw*8) = wp;
    *(short8v*)(Wn + chw*8) = wn;
    __syncthreads();
#pragma unroll
    for (int s=0;s<2;++s){
      short8v ap[2], an[2];
#pragma unroll
      for (int rt=0;rt<2;++rt){
        int g = (rt*2 + s)*4 + l4;
        int ch = g*16 + (l15 ^ (g & 7));
        ap[rt] = *(const short8v*)(Wp + ch*8);
        an[rt] = *(const short8v*)(Wn + ch*8);
      }
#pragma unroll
      for (int ht=0;ht<4;++ht){
        int hr = hw + ht*16 + l15;
        short8v b = *(const short8v*)((const char*)Ktile + hr*128 + ((s*4 + l4) ^ (hr & 7))*16);
#pragma unroll
        for (int rt=0;rt<2;++rt){
          accP[rt][ht] = __builtin_amdgcn_mfma_f32_16x16x32_bf16(ap[rt], b, accP[rt][ht], 0,0,0);
          accN[rt][ht] = __builtin_amdgcn_mfma_f32_16x16x32_bf16(an[rt], b, accN[rt][ht], 0,0,0);
        }
      }
    }
    __syncthreads();
  }

  // epilogue: scale, gate by Q (hi+lo), write via LDS staging
  float isp[2][4], isn[2][4];
#pragma unroll
  for (int rt=0;rt<2;++rt)
#pragma unroll
    for (int reg=0;reg<4;++reg){
      isp[rt][reg] = rsp[rowBase + rt*16 + l4*4 + reg];
      isn[rt][reg] = rsn[rowBase + rt*16 + l4*4 + reg];
    }
  float* Pout = (float*)smem;   // [32][260]
#pragma unroll
  for (int rt=0;rt<2;++rt)
#pragma unroll
    for (int ht=0;ht<4;++ht)
#pragma unroll
      for (int reg=0;reg<4;++reg)
        Pout[(rt*16 + l4*4 + reg)*260 + hw + ht*16 + l15] = accP[rt][ht][reg]*isp[rt][reg];
  __syncthreads();
#pragma unroll
  for (int i=0;i<8;++i){
    int row = t >> 3;
    int col = (t & 7)*4 + i*32;
    float4 pv = *(float4*)&Pout[row*260 + col];
    float4 qv = ld4bf(Qhi, Qlo, (size_t)(rowBase+row)*HID + hBase + col);
    float4 o; o.x=pv.x*qv.x; o.y=pv.y*qv.y; o.z=pv.z*qv.z; o.w=pv.w*qv.w;
    *(float4*)&outP[(size_t)(rowBase+row)*HID + hBase + col] = o;
  }
  __syncthreads();
#pragma unroll
  for (int rt=0;rt<2;++rt)
#pragma unroll
    for (int ht=0;ht<4;++ht)
#pragma unroll
      for (int reg=0;reg<4;++reg)
        Pout[(rt*16 + l4*4 + reg)*260 + hw + ht*16 + l15] = accN[rt][ht][reg]*isn[rt][reg];
  __syncthreads();
#pragma unroll
  for (int i=0;i<8;++i){
    int row = t >> 3;
    int col = (t & 7)*4 + i*32;
    float4 pv = *(float4*)&Pout[row*260 + col];
    float4 qv = ld4bf(Qhi, Qlo, (size_t)(rowBase+row)*HID + hBase + col);
    float4 o; o.x=pv.x*qv.x; o.y=pv.y*qv.y; o.z=pv.z*qv.z; o.w=pv.w*qv.w;
    *(float4*)&outN[(size_t)(rowBase+row)*HID + hBase + col] = o;
  }
}

// ============================ CSR upload (skew-independent) ============================

__global__ __launch_bounds__(256) void csr_scan(const int* __restrict__ cnt,
                                                int* __restrict__ off, int* __restrict__ woff){
  __shared__ int partial[256];
  const int t = threadIdx.x;
  const int base = t*8;
  int local[8]; int s = 0;
#pragma unroll
  for (int j=0;j<8;++j){ local[j] = s; s += cnt[base+j]; }
  partial[t] = s;
  __syncthreads();
  for (int d=1; d<256; d<<=1){
    int v = (t>=d) ? partial[t-d] : 0;
    __syncthreads();
    partial[t] += v;
    __syncthreads();
  }
  int pre = (t==0) ? 0 : partial[t-1];
#pragma unroll
  for (int j=0;j<8;++j){ int o = pre + local[j]; off[base+j]=o; woff[base+j]=o; }
  if (t==255) off[2048] = partial[255];
}

__global__ __launch_bounds__(256) void csr_fill(const int* __restrict__ gidx,
                                                const float* __restrict__ rowm,
                                                const float* __restrict__ colmax,
                                                int* __restrict__ woff,
                                                int* __restrict__ rows, float* __restrict__ wv,
                                                int* __restrict__ sid){
  int i = blockIdx.x*256 + threadIdx.x;
  int g = gidx[i];
  int p = atomicAdd(&woff[g], 1);
  rows[p] = i;
  wv[p] = __expf(rowm[i] - colmax[g]);
  sid[p] = g;
}

// 256 blocks x 64 CSR entries each: bounded serial work regardless of slot skew.
__global__ __launch_bounds__(256) void upload_scatter(
    const unsigned short* __restrict__ Qhi, const unsigned short* __restrict__ Qlo,
    const int* __restrict__ sid, const int* __restrict__ rows, const float* __restrict__ wv,
    const int* __restrict__ train, float* __restrict__ qacc)
{
  if (*train == 0) return;
  const int b = blockIdx.x, t = threadIdx.x;
  __shared__ int   s_sid[64];
  __shared__ int   s_row[64];
  __shared__ float s_w[64];
  if (t < 64){
    int p = b*64 + t;
    s_sid[t] = sid[p];
    s_row[t] = rows[p];
    s_w[t]   = wv[p];
  }
  __syncthreads();
  const int h0 = t*2;
  float a0 = 0.f, a1 = 0.f;
  int prev = s_sid[0];
#pragma unroll 4
  for (int p = 0; p < 64; ++p){
    int s = s_sid[p];
    if (s != prev){
      atomicAdd(&qacc[(size_t)prev*HID + h0],     a0);
      atomicAdd(&qacc[(size_t)prev*HID + h0 + 1], a1);
      a0 = 0.f; a1 = 0.f; prev = s;
    }
    int row = s_row[p];
    float w = s_w[p];
    unsigned h = *(const unsigned*)(Qhi + (size_t)row*HID + h0);
    unsigned l = *(const unsigned*)(Qlo + (size_t)row*HID + h0);
    a0 += w * (bf16_to_f32((unsigned short)(h & 0xffffu)) + bf16_to_f32((unsigned short)(l & 0xffffu)));
    a1 += w * (bf16_to_f32((unsigned short)(h >> 16))     + bf16_to_f32((unsigned short)(l >> 16)));
  }
  atomicAdd(&qacc[(size_t)prev*HID + h0],     a0);
  atomicAdd(&qacc[(size_t)prev*HID + h0 + 1], a1);
}

// Block per slot: mem = normalize(qacc + K) (train) or K (eval).
__global__ __launch_bounds__(256) void upload_finish(const float* __restrict__ qacc,
                                                     const float* __restrict__ Km,
                                                     const int* __restrict__ train,
                                                     float* __restrict__ mem)
{
  const int m = blockIdx.x, t = threadIdx.x;
  const int h0 = t * 2;
  float2 kv = *(const float2*)&Km[(size_t)m*HID + h0];
  if (*train == 0){
    mem[(size_t)m*HID + h0]     = kv.x;
    mem[(size_t)m*HID + h0 + 1] = kv.y;
    return;
  }
  float2 av = *(const float2*)&qacc[(size_t)m*HID + h0];
  float v0 = av.x + kv.x, v1 = av.y + kv.y;
  __shared__ float red[256];
  red[t] = v0*v0 + v1*v1;
  __syncthreads();
  for (int s = 128; s > 0; s >>= 1){
    if (t < s) red[t] += red[t + s];
    __syncthreads();
  }
  float rinv = 1.f / fmaxf(sqrtf(red[0]), 1e-12f);
  mem[(size_t)m*HID + h0]     = v0 * rinv;
  mem[(size_t)m*HID + h0 + 1] = v1 * rinv;
}

// ============================ host ============================

extern "C" void kernel_launch(void* const* d_in, const int* in_sizes, int n_in,
                              void* d_out, int out_size, void* d_ws, size_t ws_size,
                              hipStream_t stream)
{
  const float* x   = (const float*)d_in[0];
  const float* Km  = (const float*)d_in[1];
  const float* W1  = (const float*)d_in[2];
  const float* b1  = (const float*)d_in[3];
  const float* W2  = (const float*)d_in[4];
  const float* b2  = (const float*)d_in[5];
  const float* W3  = (const float*)d_in[6];
  const float* b3  = (const float*)d_in[7];
  const float* Wd  = (const float*)d_in[8];
  const float* bd  = (const float*)d_in[9];
  const int* train = (const int*)d_in[10];

  float* out  = (float*)d_out;
  float* pred = out;
  float* outN = out + 16384;
  float* outP = out + 16384 + 8388608;
  float* memo = out + 16384 + 2*8388608;

  char* ws = (char*)d_ws;
  unsigned short* Qhi   = (unsigned short*)(ws + 0);           // 16,777,216
  unsigned short* Qlo   = (unsigned short*)(ws + 16777216);    // 16,777,216
  // R0 region (aliased: xpad/h1/h2 all dead before Sb is written)
  unsigned short* xph   = (unsigned short*)(ws + 33554432);    // 12,582,912
  unsigned short* xpl   = (unsigned short*)(ws + 46137344);    // 12,582,912
  unsigned short* h1h   = (unsigned short*)(ws + 58720256);    // 16,777,216
  unsigned short* h1l   = (unsigned short*)(ws + 75497472);    // 16,777,216
  unsigned short* h2h   = (unsigned short*)(ws + 92274688);    // 16,777,216
  unsigned short* h2l   = (unsigned short*)(ws + 109051904);   // 16,777,216 (R0 end 125,829,120)
  unsigned short* Sb    = (unsigned short*)(ws + 33554432);    // 67,108,864 (aliases R0)
  unsigned short* Khi   = (unsigned short*)(ws + 125829120);   //  2,097,152
  unsigned short* Klo   = (unsigned short*)(ws + 127926272);   //  2,097,152
  unsigned short* Kt    = (unsigned short*)(ws + 130023424);   //  2,097,152
  unsigned short* W1ph  = (unsigned short*)(ws + 132120576);   //    393,216
  unsigned short* W1pl  = (unsigned short*)(ws + 132513792);   //    393,216
  unsigned short* W2h   = (unsigned short*)(ws + 132907008);   //    524,288
  unsigned short* W2l   = (unsigned short*)(ws + 133431296);   //    524,288
  unsigned short* W3h   = (unsigned short*)(ws + 133955584);   //    524,288
  unsigned short* W3l   = (unsigned short*)(ws + 134479872);   //    524,288
  float* pmax    = (float*)(ws + 135004160);                   //  2,097,152
  int*   pcol    = (int*)  (ws + 137101312);                   //  2,097,152
  float* psum    = (float*)(ws + 139198464);                   //  2,097,152
  float* pnmax   = (float*)(ws + 141295616);                   //  2,097,152
  float* pnsum   = (float*)(ws + 143392768);                   //  2,097,152
  float* pcolmax = (float*)(ws + 145489920);                   //  4,194,304 (256 rows used)
  float* rowm    = (float*)(ws + 149684224);
  float* rsp     = (float*)(ws + 149749760);
  float* rmn     = (float*)(ws + 149815296);
  float* rsn     = (float*)(ws + 149880832);
  int*   gidx    = (int*)  (ws + 149946368);
  float* colmax  = (float*)(ws + 150011904);
  int*   cnt     = (int*)  (ws + 150020096);                   //      8,192
  int*   off     = (int*)  (ws + 150028288);                   //      8,448 (2049 ints)
  int*   woff    = (int*)  (ws + 150036736);                   //      8,192
  int*   rows    = (int*)  (ws + 150044928);                   //     65,536
  float* wv      = (float*)(ws + 150110464);                   //     65,536
  int*   sid     = (int*)  (ws + 150176000);                   //     65,536
  float* qacc    = (float*)(ws + 150241536);                   //  4,194,304
  const size_t NEED = 154435840ull;
  if (ws_size < NEED) return;  // harness provides >= 155 MB (proven round 2)

  dim3 blk(256);
  // conversions
  cvt_pad_split<<<(N_ROWS*KP1/4 + 255)/256, blk, 0, stream>>>(x,  xph,  xpl,  N_ROWS, D_INN, KP1);
  cvt_pad_split<<<(HID*KP1/4 + 255)/256,    blk, 0, stream>>>(W1, W1ph, W1pl, HID,    D_INN, KP1);
  cvt_split<<<HID*HID/2048,     blk, 0, stream>>>(W2, W2h, W2l, HID*HID);
  cvt_split<<<HID*HID/2048,     blk, 0, stream>>>(W3, W3h, W3l, HID*HID);
  cvt_split<<<M_SLOTS*HID/2048, blk, 0, stream>>>(Km, Khi, Klo, M_SLOTS*HID);
  kt_kernel<<<dim3(32, 8), blk, 0, stream>>>(Km, Kt);

  // MLP (split-bf16 MFMA); layer 3 fuses the pred dot (pred pre-init'd to bd)
  mlp_gemm<<<dim3(N_ROWS/64, 4), blk, 0, stream>>>(xph, xpl, W1ph, W1pl, b1, h1h, h1l, KP1,
                                                   (const float*)nullptr, (float*)nullptr);
  mlp_gemm<<<dim3(N_ROWS/64, 4), blk, 0, stream>>>(h1h, h1l, W2h, W2l, b2, h2h, h2l, HID,
                                                   (const float*)nullptr, (float*)nullptr);
  pred_init<<<N_ROWS/256, blk, 0, stream>>>(pred, bd);
  mlp_gemm<<<dim3(N_ROWS/64, 4), blk, 0, stream>>>(h2h, h2l, W3h, W3l, b3, Qhi, Qlo, HID,
                                                   Wd, pred);

  // attention stats + PV
  sgemm_stats<<<dim3(16, 128), blk, 0, stream>>>(Qhi, Qlo, Khi, Klo, Sb,
                                                 pmax, pcol, psum, pnmax, pnsum, pcolmax);
  hipMemsetAsync(cnt, 0, M_SLOTS*sizeof(int), stream);
  merge_rows<<<64, blk, 0, stream>>>(pmax, pcol, psum, pnmax, pnsum, rowm, rsp, rmn, rsn, gidx, cnt);
  merge_cols<<<8, blk, 0, stream>>>(pcolmax, colmax);
  pv2<<<dim3(2, 512), blk, 0, stream>>>(Sb, Kt, rowm, rsp, rmn, rsn, Qhi, Qlo, outP, outN);

  // upload via CSR + bounded scatter
  hipMemsetAsync(qacc, 0, M_SLOTS*HID*sizeof(float), stream);
  csr_scan<<<1, blk, 0, stream>>>(cnt, off, woff);
  csr_fill<<<N_ROWS/256, blk, 0, stream>>>(gidx, rowm, colmax, woff, rows, wv, sid);
  upload_scatter<<<N_ROWS/64, blk, 0, stream>>>(Qhi, Qlo, sid, rows, wv, train, qacc);
  upload_finish<<<M_SLOTS, blk, 0, stream>>>(qacc, Km, train, memo);
}

// Round 7
// 577.319 us; speedup vs baseline: 1.0306x; 1.0306x over previous
//
#include <hip/hip_runtime.h>
#include <math.h>

// Problem constants (fixed by the reference).
#define N_ROWS 16384
#define D_INN  360
#define KP1    384      // D_INN padded to multiple of 64
#define HID    512
#define M_SLOTS 2048

typedef __attribute__((ext_vector_type(8))) short short8v;
typedef __attribute__((ext_vector_type(4))) float f32x4;
typedef __attribute__((address_space(1))) unsigned int as1_uint;
typedef __attribute__((address_space(3))) unsigned int as3_uint;

// ---- bf16 helpers (manual, RNE) ----
__device__ __forceinline__ unsigned short bf16_rne(float f){
  unsigned u = __float_as_uint(f);
  unsigned r = u + 0x7FFFu + ((u >> 16) & 1u);
  return (unsigned short)(r >> 16);
}
__device__ __forceinline__ float bf16_to_f32(unsigned short h){
  return __uint_as_float(((unsigned)h) << 16);
}

__device__ __forceinline__ void glds16(const void* g, void* l){
  __builtin_amdgcn_global_load_lds((const as1_uint*)g, (as3_uint*)l, 16, 0, 0);
}

// reconstruct 4 consecutive f32 from hi/lo bf16 pair arrays
__device__ __forceinline__ float4 ld4bf(const unsigned short* hi, const unsigned short* lo, size_t off){
  uint2 h = *(const uint2*)(hi + off);
  uint2 l = *(const uint2*)(lo + off);
  float4 r;
  r.x = bf16_to_f32((unsigned short)(h.x & 0xffffu)) + bf16_to_f32((unsigned short)(l.x & 0xffffu));
  r.y = bf16_to_f32((unsigned short)(h.x >> 16))     + bf16_to_f32((unsigned short)(l.x >> 16));
  r.z = bf16_to_f32((unsigned short)(h.y & 0xffffu)) + bf16_to_f32((unsigned short)(l.y & 0xffffu));
  r.w = bf16_to_f32((unsigned short)(h.y >> 16))     + bf16_to_f32((unsigned short)(l.y >> 16));
  return r;
}

// ============================ conversion kernels ============================

// split f32 -> bf16 hi + bf16 lo (residual); nelem multiple of 2048
__global__ __launch_bounds__(256) void cvt_split(const float* __restrict__ src,
                                                 unsigned short* __restrict__ hi,
                                                 unsigned short* __restrict__ lo,
                                                 int nelem)
{
  int idx = (blockIdx.x*256 + threadIdx.x) * 8;
  if (idx >= nelem) return;
  float4 a = *(const float4*)&src[idx];
  float4 b = *(const float4*)&src[idx+4];
  float v[8] = {a.x,a.y,a.z,a.w,b.x,b.y,b.z,b.w};
  short8v hv, lv;
#pragma unroll
  for (int e=0;e<8;++e){
    unsigned short h = bf16_rne(v[e]);
    float hf = bf16_to_f32(h);
    hv[e] = (short)h;
    lv[e] = (short)bf16_rne(v[e] - hf);
  }
  *(short8v*)&hi[idx] = hv;
  *(short8v*)&lo[idx] = lv;
}

// f32 [R][Ksrc] -> split bf16 [R][Kp] with zero padding for c >= Ksrc.
__global__ __launch_bounds__(256) void cvt_pad_split(const float* __restrict__ src,
                                                     unsigned short* __restrict__ hi,
                                                     unsigned short* __restrict__ lo,
                                                     int R, int Ksrc, int Kp)
{
  long long e0 = ((long long)blockIdx.x*256 + threadIdx.x) * 4;
  if (e0 >= (long long)R*Kp) return;
  int row = (int)(e0 / Kp), c = (int)(e0 % Kp);
  unsigned short h4[4], l4[4];
  if (c < Ksrc){
    float4 v = *(const float4*)&src[(size_t)row*Ksrc + c];
    float vv[4] = {v.x, v.y, v.z, v.w};
#pragma unroll
    for (int e=0;e<4;++e){
      unsigned short h = bf16_rne(vv[e]);
      h4[e] = h;
      l4[e] = bf16_rne(vv[e] - bf16_to_f32(h));
    }
  } else {
#pragma unroll
    for (int e=0;e<4;++e){ h4[e]=0; l4[e]=0; }
  }
  *(uint2*)&hi[(size_t)row*Kp + c] = *(uint2*)h4;
  *(uint2*)&lo[(size_t)row*Kp + c] = *(uint2*)l4;
}

// Kt[h][slot] = bf16(K[slot][h])  -- transposed bf16 copy of memory matrix
__global__ __launch_bounds__(256) void kt_kernel(const float* __restrict__ K,
                                                 unsigned short* __restrict__ Kt)
{
  __shared__ float tile[64][65];
  const int sb = blockIdx.x * 64;  // slot base
  const int hb = blockIdx.y * 64;  // h base
  const int t = threadIdx.x;
  {
    int r = t >> 2, cq = t & 3;
#pragma unroll
    for (int q=0;q<4;++q){
      float4 v = *(const float4*)&K[(size_t)(sb+r)*HID + hb + cq*16 + q*4];
      tile[r][cq*16+q*4+0]=v.x; tile[r][cq*16+q*4+1]=v.y;
      tile[r][cq*16+q*4+2]=v.z; tile[r][cq*16+q*4+3]=v.w;
    }
  }
  __syncthreads();
  {
    int hl = t >> 2, sq = t & 3;
    unsigned short w16[16];
#pragma unroll
    for (int q=0;q<16;++q) w16[q] = bf16_rne(tile[sq*16+q][hl]);
    *(uint4*)&Kt[(size_t)(hb+hl)*M_SLOTS + sb + sq*16]     = *(uint4*)&w16[0];
    *(uint4*)&Kt[(size_t)(hb+hl)*M_SLOTS + sb + sq*16 + 8] = *(uint4*)&w16[8];
  }
}

// pred[i] = bd (init before mlp3's fused atomic dot)
__global__ __launch_bounds__(256) void pred_init(float* __restrict__ pred, const float* __restrict__ bd){
  pred[blockIdx.x*256 + threadIdx.x] = bd[0];
}

// ============================ MLP GEMM (3-term split bf16 MFMA) ============================
// Optional fused pred: when predp != nullptr, accumulate row-dot with Wd via atomics.
__global__ __launch_bounds__(256) void mlp_gemm(
    const unsigned short* __restrict__ Ah_g, const unsigned short* __restrict__ Al_g,
    const unsigned short* __restrict__ Wh_g, const unsigned short* __restrict__ Wl_g,
    const float* __restrict__ bias,
    unsigned short* __restrict__ Ohi, unsigned short* __restrict__ Olo,
    int Kp, const float* __restrict__ Wd, float* __restrict__ predp)
{
  __shared__ char smem[49152];
  unsigned short* Ah = (unsigned short*)smem;            // [64][64] bf16, chunk-swizzled
  unsigned short* Al = (unsigned short*)(smem + 8192);
  unsigned short* Bh = (unsigned short*)(smem + 16384);  // [128][64]
  unsigned short* Bl = (unsigned short*)(smem + 32768);
  const int t = threadIdx.x;
  const int lane = t & 63, w = t >> 6;
  const int l15 = lane & 15, l4 = lane >> 4;
  const int rowBase = blockIdx.x * 64;
  const int colBase = blockIdx.y * 128;
  const int wr = (w >> 1) * 32;
  const int wc = (w & 1) * 64;

  f32x4 acc[2][4];
#pragma unroll
  for (int i=0;i<2;++i)
#pragma unroll
    for (int j=0;j<4;++j) acc[i][j] = (f32x4){0.f,0.f,0.f,0.f};

  const int nkt = Kp >> 6;
  for (int kt = 0; kt < nkt; ++kt){
    const int k0 = kt * 64;
#pragma unroll
    for (int p = 0; p < 2; ++p){
      int idx = p*256 + t;
      int r = idx >> 3, c = idx & 7;
      int cc = c ^ (r & 7);
      size_t go = (size_t)(rowBase + r) * Kp + (k0 + cc*8);
      glds16(Ah_g + go, (char*)Ah + idx*16);
      glds16(Al_g + go, (char*)Al + idx*16);
    }
#pragma unroll
    for (int p = 0; p < 4; ++p){
      int idx = p*256 + t;
      int r = idx >> 3, c = idx & 7;
      int cc = c ^ (r & 7);
      size_t go = (size_t)(colBase + r) * Kp + (k0 + cc*8);
      glds16(Wh_g + go, (char*)Bh + idx*16);
      glds16(Wl_g + go, (char*)Bl + idx*16);
    }
    __syncthreads();

#pragma unroll
    for (int s = 0; s < 2; ++s){
      short8v a_h[2], a_l[2], b_h[4], b_l[4];
#pragma unroll
      for (int rt = 0; rt < 2; ++rt){
        int r = wr + rt*16 + l15;
        int off = r*128 + ((s*4 + l4) ^ (r & 7))*16;
        a_h[rt] = *(const short8v*)((const char*)Ah + off);
        a_l[rt] = *(const short8v*)((const char*)Al + off);
      }
#pragma unroll
      for (int ct = 0; ct < 4; ++ct){
        int r = wc + ct*16 + l15;
        int off = r*128 + ((s*4 + l4) ^ (r & 7))*16;
        b_h[ct] = *(const short8v*)((const char*)Bh + off);
        b_l[ct] = *(const short8v*)((const char*)Bl + off);
      }
#pragma unroll
      for (int rt = 0; rt < 2; ++rt)
#pragma unroll
        for (int ct = 0; ct < 4; ++ct){
          acc[rt][ct] = __builtin_amdgcn_mfma_f32_16x16x32_bf16(a_h[rt], b_h[ct], acc[rt][ct], 0,0,0);
          acc[rt][ct] = __builtin_amdgcn_mfma_f32_16x16x32_bf16(a_h[rt], b_l[ct], acc[rt][ct], 0,0,0);
          acc[rt][ct] = __builtin_amdgcn_mfma_f32_16x16x32_bf16(a_l[rt], b_h[ct], acc[rt][ct], 0,0,0);
        }
    }
    __syncthreads();
  }

  // epilogue: bias + relu, split hi/lo, stage through LDS for coalesced writes
  float bcol[4];
#pragma unroll
  for (int ct=0; ct<4; ++ct) bcol[ct] = bias[colBase + wc + ct*16 + l15];
  unsigned short* Sout = (unsigned short*)smem;  // [64][136]
#pragma unroll
  for (int rt=0; rt<2; ++rt)
#pragma unroll
    for (int ct=0; ct<4; ++ct)
#pragma unroll
      for (int reg=0; reg<4; ++reg){
        float v = acc[rt][ct][reg] + bcol[ct];
        v = v > 0.f ? v : 0.f;
        acc[rt][ct][reg] = v;
        Sout[(wr + rt*16 + l4*4 + reg)*136 + wc + ct*16 + l15] = bf16_rne(v);
      }

  // fused pred partial (last layer only): row-dot over this block's 128 cols
  if (predp){
    float wdv[4];
#pragma unroll
    for (int ct=0; ct<4; ++ct) wdv[ct] = Wd[colBase + wc + ct*16 + l15];
#pragma unroll
    for (int rt=0; rt<2; ++rt)
#pragma unroll
      for (int reg=0; reg<4; ++reg){
        float pd = acc[rt][0][reg]*wdv[0] + acc[rt][1][reg]*wdv[1]
                 + acc[rt][2][reg]*wdv[2] + acc[rt][3][reg]*wdv[3];
#pragma unroll
        for (int d=1; d<16; d<<=1) pd += __shfl_xor(pd, d);
        if (l15 == 0)
          atomicAdd(&predp[rowBase + wr + rt*16 + l4*4 + reg], pd);
      }
  }

  __syncthreads();
#pragma unroll
  for (int p = 0; p < 4; ++p){
    int row = (t >> 4) + p*16;
    int c8 = (t & 15) * 8;
    uint4 v = *(uint4*)&Sout[row*136 + c8];
    *(uint4*)&Ohi[(size_t)(rowBase+row)*HID + colBase + c8] = v;
  }
  __syncthreads();
#pragma unroll
  for (int rt=0; rt<2; ++rt)
#pragma unroll
    for (int ct=0; ct<4; ++ct)
#pragma unroll
      for (int reg=0; reg<4; ++reg){
        float v = acc[rt][ct][reg];
        unsigned short h = bf16_rne(v);
        Sout[(wr + rt*16 + l4*4 + reg)*136 + wc + ct*16 + l15] = bf16_rne(v - bf16_to_f32(h));
      }
  __syncthreads();
#pragma unroll
  for (int p = 0; p < 4; ++p){
    int row = (t >> 4) + p*16;
    int c8 = (t & 15) * 8;
    uint4 v = *(uint4*)&Sout[row*136 + c8];
    *(uint4*)&Olo[(size_t)(rowBase+row)*HID + colBase + c8] = v;
  }
}

// ============================ S GEMM + stats (proven r5 structure) ============================
// BM=64 x BN=128, BK=64; all four operands (Q/K hi+lo) LDS-staged via glds16.
// grid (16 colblocks, 256 rowblocks).
__global__ __launch_bounds__(256) void sgemm_stats(
    const unsigned short* __restrict__ Qhi, const unsigned short* __restrict__ Qlo,
    const unsigned short* __restrict__ Khi, const unsigned short* __restrict__ Klo,
    unsigned short* __restrict__ Sb,
    float* __restrict__ pmax, int* __restrict__ pcol,
    float* __restrict__ psum, float* __restrict__ pnmax, float* __restrict__ pnsum,
    float* __restrict__ pcolmax)
{
  __shared__ char smem[49152];
  unsigned short* Ah = (unsigned short*)smem;
  unsigned short* Al = (unsigned short*)(smem + 8192);
  unsigned short* Bh = (unsigned short*)(smem + 16384);
  unsigned short* Bl = (unsigned short*)(smem + 32768);
  const int t = threadIdx.x;
  const int lane = t & 63, w = t >> 6;
  const int l15 = lane & 15, l4 = lane >> 4;
  const int cb = blockIdx.x;      // 0..15  col block
  const int rb = blockIdx.y;      // 0..255 row block
  const int rowBase = rb * 64;
  const int colBase = cb * 128;
  const int wr = (w >> 1) * 32;
  const int wc = (w & 1) * 64;

  f32x4 acc[2][4];
#pragma unroll
  for (int i=0;i<2;++i)
#pragma unroll
    for (int j=0;j<4;++j) acc[i][j] = (f32x4){0.f,0.f,0.f,0.f};

  for (int kt = 0; kt < 8; ++kt){
    const int k0 = kt * 64;
#pragma unroll
    for (int p = 0; p < 2; ++p){
      int idx = p*256 + t;
      int r = idx >> 3, c = idx & 7;
      int cc = c ^ (r & 7);
      size_t go = (size_t)(rowBase + r) * HID + (k0 + cc*8);
      glds16(Qhi + go, (char*)Ah + idx*16);
      glds16(Qlo + go, (char*)Al + idx*16);
    }
#pragma unroll
    for (int p = 0; p < 4; ++p){
      int idx = p*256 + t;
      int r = idx >> 3, c = idx & 7;
      int cc = c ^ (r & 7);
      size_t go = (size_t)(colBase + r) * HID + (k0 + cc*8);
      glds16(Khi + go, (char*)Bh + idx*16);
      glds16(Klo + go, (char*)Bl + idx*16);
    }
    __syncthreads();

#pragma unroll
    for (int s = 0; s < 2; ++s){
      short8v a_h[2], a_l[2], b_h[4], b_l[4];
#pragma unroll
      for (int rt = 0; rt < 2; ++rt){
        int r = wr + rt*16 + l15;
        int off = r*128 + ((s*4 + l4) ^ (r & 7))*16;
        a_h[rt] = *(const short8v*)((const char*)Ah + off);
        a_l[rt] = *(const short8v*)((const char*)Al + off);
      }
#pragma unroll
      for (int ct = 0; ct < 4; ++ct){
        int r = wc + ct*16 + l15;
        int off = r*128 + ((s*4 + l4) ^ (r & 7))*16;
        b_h[ct] = *(const short8v*)((const char*)Bh + off);
        b_l[ct] = *(const short8v*)((const char*)Bl + off);
      }
#pragma unroll
      for (int rt = 0; rt < 2; ++rt)
#pragma unroll
        for (int ct = 0; ct < 4; ++ct){
          acc[rt][ct] = __builtin_amdgcn_mfma_f32_16x16x32_bf16(a_h[rt], b_h[ct], acc[rt][ct], 0,0,0);
          acc[rt][ct] = __builtin_amdgcn_mfma_f32_16x16x32_bf16(a_h[rt], b_l[ct], acc[rt][ct], 0,0,0);
          acc[rt][ct] = __builtin_amdgcn_mfma_f32_16x16x32_bf16(a_l[rt], b_h[ct], acc[rt][ct], 0,0,0);
        }
    }
    __syncthreads();
  }

  // ---- row stats (per wave over its 64-col half) ----
#pragma unroll
  for (int rt = 0; rt < 2; ++rt){
#pragma unroll
    for (int reg = 0; reg < 4; ++reg){
      float v0 = acc[rt][0][reg], v1 = acc[rt][1][reg];
      float v2 = acc[rt][2][reg], v3 = acc[rt][3][reg];
      float bvv = v0; int bcc = colBase + wc + l15;
      if (v1 > bvv){ bvv = v1; bcc = colBase + wc + 16 + l15; }
      if (v2 > bvv){ bvv = v2; bcc = colBase + wc + 32 + l15; }
      if (v3 > bvv){ bvv = v3; bcc = colBase + wc + 48 + l15; }
      float mnv = fminf(fminf(v0,v1), fminf(v2,v3));
#pragma unroll
      for (int d = 1; d < 16; d <<= 1){
        float ov = __shfl_xor(bvv, d);
        int   oc = __shfl_xor(bcc, d);
        float om = __shfl_xor(mnv, d);
        if (ov > bvv || (ov == bvv && oc < bcc)){ bvv = ov; bcc = oc; }
        mnv = fminf(mnv, om);
      }
      float sp = __expf(v0-bvv)+__expf(v1-bvv)+__expf(v2-bvv)+__expf(v3-bvv);
      float sn = __expf(mnv-v0)+__expf(mnv-v1)+__expf(mnv-v2)+__expf(mnv-v3);
#pragma unroll
      for (int d = 1; d < 16; d <<= 1){ sp += __shfl_xor(sp,d); sn += __shfl_xor(sn,d); }
      if (l15 == 0){
        int row = rowBase + wr + rt*16 + l4*4 + reg;
        size_t pi = (size_t)row*32 + cb*2 + (w & 1);
        pmax[pi] = bvv; pcol[pi] = bcc; psum[pi] = sp;
        pnmax[pi] = -mnv; pnsum[pi] = sn;
      }
    }
  }

  // ---- per-column tile max ----
#pragma unroll
  for (int ct = 0; ct < 4; ++ct){
    float cm = -1e30f;
#pragma unroll
    for (int rt=0; rt<2; ++rt)
#pragma unroll
      for (int reg=0; reg<4; ++reg) cm = fmaxf(cm, acc[rt][ct][reg]);
    cm = fmaxf(cm, __shfl_xor(cm, 16));
    cm = fmaxf(cm, __shfl_xor(cm, 32));
    if (l4 == 0)
      pcolmax[(size_t)(rb*2 + (w>>1))*M_SLOTS + colBase + wc + ct*16 + l15] = cm;
  }

  // ---- S bf16 write (staged through LDS for coalescing) ----
  __syncthreads();
  unsigned short* Sout = (unsigned short*)smem;  // [64][136]
#pragma unroll
  for (int rt=0; rt<2; ++rt)
#pragma unroll
    for (int ct=0; ct<4; ++ct)
#pragma unroll
      for (int reg=0; reg<4; ++reg)
        Sout[(wr + rt*16 + l4*4 + reg)*136 + wc + ct*16 + l15] = bf16_rne(acc[rt][ct][reg]);
  __syncthreads();
#pragma unroll
  for (int p = 0; p < 4; ++p){
    int row = (t >> 4) + p*16;
    int c8 = (t & 15) * 8;
    uint4 v = *(uint4*)&Sout[row*136 + c8];
    *(uint4*)&Sb[(size_t)(rowBase+row)*M_SLOTS + colBase + c8] = v;
  }
}

__global__ __launch_bounds__(256) void merge_rows(
    const float* __restrict__ pmax, const int* __restrict__ pcol,
    const float* __restrict__ psum, const float* __restrict__ pnmax,
    const float* __restrict__ pnsum,
    float* __restrict__ rowm, float* __restrict__ rsp,
    float* __restrict__ rmn, float* __restrict__ rsn, int* __restrict__ gidx,
    int* __restrict__ cnt)
{
  int row = blockIdx.x*256 + threadIdx.x;
  const size_t base = (size_t)row*32;
  float m = -1e30f; int g = 0;
  for (int i=0;i<32;++i){
    float v = pmax[base+i];
    if (v > m){ m = v; g = pcol[base+i]; }
  }
  float s = 0.f;
  for (int i=0;i<32;++i) s += psum[base+i] * __expf(pmax[base+i]-m);
  float mn = -1e30f;
  for (int i=0;i<32;++i) mn = fmaxf(mn, pnmax[base+i]);
  float sn = 0.f;
  for (int i=0;i<32;++i) sn += pnsum[base+i] * __expf(pnmax[base+i]-mn);
  rowm[row]=m; gidx[row]=g; rsp[row]=1.f/s; rmn[row]=mn; rsn[row]=1.f/sn;
  atomicAdd(&cnt[g], 1);   // fused csr_count
}

__global__ __launch_bounds__(256) void merge_cols(const float* __restrict__ pcolmax,
                                                  float* __restrict__ colmax)
{
  int c = blockIdx.x*256 + threadIdx.x;
  float m = -1e30f;
  for (int r=0;r<512;++r) m = fmaxf(m, pcolmax[(size_t)r*M_SLOTS + c]);
  colmax[c] = m;
}

// ============================ PV (S read once) ============================
#define PV_RB 32
#define PV_HB 256
__global__ __launch_bounds__(256, 3) void pv2(
    const unsigned short* __restrict__ Sb, const unsigned short* __restrict__ Kt,
    const float* __restrict__ rowm, const float* __restrict__ rsp,
    const float* __restrict__ rmn, const float* __restrict__ rsn,
    const unsigned short* __restrict__ Qhi, const unsigned short* __restrict__ Qlo,
    float* __restrict__ outP, float* __restrict__ outN)
{
  __shared__ char smem[40960];
  unsigned short* Ktile = (unsigned short*)smem;          // [256 h][64 slots], chunk-swizzled, 32KB
  unsigned short* Wp = (unsigned short*)(smem + 32768);   // frag-ordered weights, 4KB
  unsigned short* Wn = (unsigned short*)(smem + 36864);   // 4KB
  const int t = threadIdx.x, lane = t & 63, w = t >> 6;
  const int l15 = lane & 15, l4 = lane >> 4;
  const int rowBase = blockIdx.y * PV_RB;
  const int hBase = blockIdx.x * PV_HB;
  const int hw = w * 64;
  const int rS = t >> 3;
  const int c8 = t & 7;
  const float mp = rowm[rowBase + rS], mn = rmn[rowBase + rS];
  const int rtw = rS >> 4;
  const int sw = c8 >> 2, l4w = c8 & 3;
  const int gw = (rtw*2 + sw)*4 + l4w;
  const int chw = gw*16 + ((rS & 15) ^ (gw & 7));

  f32x4 accP[2][4], accN[2][4];
#pragma unroll
  for (int i=0;i<2;++i)
#pragma unroll
    for (int j=0;j<4;++j){ accP[i][j]=(f32x4){0.f,0.f,0.f,0.f}; accN[i][j]=(f32x4){0.f,0.f,0.f,0.f}; }

  for (int kt = 0; kt < 32; ++kt){
    const int k0 = kt*64;
#pragma unroll
    for (int p=0;p<8;++p){
      int idx = p*256 + t;
      int r = idx >> 3, c = idx & 7;
      int cc = c ^ (r & 7);
      glds16(Kt + (size_t)(hBase + r)*M_SLOTS + k0 + cc*8, (char*)Ktile + idx*16);
    }
    short8v sv = *(const short8v*)&Sb[(size_t)(rowBase + rS)*M_SLOTS + k0 + c8*8];
    short8v wp, wn;
#pragma unroll
    for (int e=0;e<8;++e){
      float sval = bf16_to_f32((unsigned short)sv[e]);
      wp[e] = (short)bf16_rne(__expf(sval - mp));
      wn[e] = (short)bf16_rne(__expf(-sval - mn));
    }
    *(short8v*)(Wp + chw*8) = wp;
    *(short8v*)(Wn + chw*8) = wn;
    __syncthreads();
#pragma unroll
    for (int s=0;s<2;++s){
      short8v ap[2], an[2];
#pragma unroll
      for (int rt=0;rt<2;++rt){
        int g = (rt*2 + s)*4 + l4;
        int ch = g*16 + (l15 ^ (g & 7));
        ap[rt] = *(const short8v*)(Wp + ch*8);
        an[rt] = *(const short8v*)(Wn + ch*8);
      }
#pragma unroll
      for (int ht=0;ht<4;++ht){
        int hr = hw + ht*16 + l15;
        short8v b = *(const short8v*)((const char*)Ktile + hr*128 + ((s*4 + l4) ^ (hr & 7))*16);
#pragma unroll
        for (int rt=0;rt<2;++rt){
          accP[rt][ht] = __builtin_amdgcn_mfma_f32_16x16x32_bf16(ap[rt], b, accP[rt][ht], 0,0,0);
          accN[rt][ht] = __builtin_amdgcn_mfma_f32_16x16x32_bf16(an[rt], b, accN[rt][ht], 0,0,0);
        }
      }
    }
    __syncthreads();
  }

  // epilogue: scale, gate by Q (hi+lo), write via LDS staging
  float isp[2][4], isn[2][4];
#pragma unroll
  for (int rt=0;rt<2;++rt)
#pragma unroll
    for (int reg=0;reg<4;++reg){
      isp[rt][reg] = rsp[rowBase + rt*16 + l4*4 + reg];
      isn[rt][reg] = rsn[rowBase + rt*16 + l4*4 + reg];
    }
  float* Pout = (float*)smem;   // [32][260]
#pragma unroll
  for (int rt=0;rt<2;++rt)
#pragma unroll
    for (int ht=0;ht<4;++ht)
#pragma unroll
      for (int reg=0;reg<4;++reg)
        Pout[(rt*16 + l4*4 + reg)*260 + hw + ht*16 + l15] = accP[rt][ht][reg]*isp[rt][reg];
  __syncthreads();
#pragma unroll
  for (int i=0;i<8;++i){
    int row = t >> 3;
    int col = (t & 7)*4 + i*32;
    float4 pv = *(float4*)&Pout[row*260 + col];
    float4 qv = ld4bf(Qhi, Qlo, (size_t)(rowBase+row)*HID + hBase + col);
    float4 o; o.x=pv.x*qv.x; o.y=pv.y*qv.y; o.z=pv.z*qv.z; o.w=pv.w*qv.w;
    *(float4*)&outP[(size_t)(rowBase+row)*HID + hBase + col] = o;
  }
  __syncthreads();
#pragma unroll
  for (int rt=0;rt<2;++rt)
#pragma unroll
    for (int ht=0;ht<4;++ht)
#pragma unroll
      for (int reg=0;reg<4;++reg)
        Pout[(rt*16 + l4*4 + reg)*260 + hw + ht*16 + l15] = accN[rt][ht][reg]*isn[rt][reg];
  __syncthreads();
#pragma unroll
  for (int i=0;i<8;++i){
    int row = t >> 3;
    int col = (t & 7)*4 + i*32;
    float4 pv = *(float4*)&Pout[row*260 + col];
    float4 qv = ld4bf(Qhi, Qlo, (size_t)(rowBase+row)*HID + hBase + col);
    float4 o; o.x=pv.x*qv.x; o.y=pv.y*qv.y; o.z=pv.z*qv.z; o.w=pv.w*qv.w;
    *(float4*)&outN[(size_t)(rowBase+row)*HID + hBase + col] = o;
  }
}

// ============================ CSR upload (skew-independent) ============================

__global__ __launch_bounds__(256) void csr_scan(const int* __restrict__ cnt,
                                                int* __restrict__ off, int* __restrict__ woff){
  __shared__ int partial[256];
  const int t = threadIdx.x;
  const int base = t*8;
  int local[8]; int s = 0;
#pragma unroll
  for (int j=0;j<8;++j){ local[j] = s; s += cnt[base+j]; }
  partial[t] = s;
  __syncthreads();
  for (int d=1; d<256; d<<=1){
    int v = (t>=d) ? partial[t-d] : 0;
    __syncthreads();
    partial[t] += v;
    __syncthreads();
  }
  int pre = (t==0) ? 0 : partial[t-1];
#pragma unroll
  for (int j=0;j<8;++j){ int o = pre + local[j]; off[base+j]=o; woff[base+j]=o; }
  if (t==255) off[2048] = partial[255];
}

__global__ __launch_bounds__(256) void csr_fill(const int* __restrict__ gidx,
                                                const float* __restrict__ rowm,
                                                const float* __restrict__ colmax,
                                                int* __restrict__ woff,
                                                int* __restrict__ rows, float* __restrict__ wv,
                                                int* __restrict__ sid){
  int i = blockIdx.x*256 + threadIdx.x;
  int g = gidx[i];
  int p = atomicAdd(&woff[g], 1);
  rows[p] = i;
  wv[p] = __expf(rowm[i] - colmax[g]);
  sid[p] = g;
}

// 256 blocks x 64 CSR entries each: bounded serial work regardless of slot skew.
__global__ __launch_bounds__(256) void upload_scatter(
    const unsigned short* __restrict__ Qhi, const unsigned short* __restrict__ Qlo,
    const int* __restrict__ sid, const int* __restrict__ rows, const float* __restrict__ wv,
    const int* __restrict__ train, float* __restrict__ qacc)
{
  if (*train == 0) return;
  const int b = blockIdx.x, t = threadIdx.x;
  __shared__ int   s_sid[64];
  __shared__ int   s_row[64];
  __shared__ float s_w[64];
  if (t < 64){
    int p = b*64 + t;
    s_sid[t] = sid[p];
    s_row[t] = rows[p];
    s_w[t]   = wv[p];
  }
  __syncthreads();
  const int h0 = t*2;
  float a0 = 0.f, a1 = 0.f;
  int prev = s_sid[0];
#pragma unroll 4
  for (int p = 0; p < 64; ++p){
    int s = s_sid[p];
    if (s != prev){
      atomicAdd(&qacc[(size_t)prev*HID + h0],     a0);
      atomicAdd(&qacc[(size_t)prev*HID + h0 + 1], a1);
      a0 = 0.f; a1 = 0.f; prev = s;
    }
    int row = s_row[p];
    float w = s_w[p];
    unsigned h = *(const unsigned*)(Qhi + (size_t)row*HID + h0);
    unsigned l = *(const unsigned*)(Qlo + (size_t)row*HID + h0);
    a0 += w * (bf16_to_f32((unsigned short)(h & 0xffffu)) + bf16_to_f32((unsigned short)(l & 0xffffu)));
    a1 += w * (bf16_to_f32((unsigned short)(h >> 16))     + bf16_to_f32((unsigned short)(l >> 16)));
  }
  atomicAdd(&qacc[(size_t)prev*HID + h0],     a0);
  atomicAdd(&qacc[(size_t)prev*HID + h0 + 1], a1);
}

// Block per slot: mem = normalize(qacc + K) (train) or K (eval).
__global__ __launch_bounds__(256) void upload_finish(const float* __restrict__ qacc,
                                                     const float* __restrict__ Km,
                                                     const int* __restrict__ train,
                                                     float* __restrict__ mem)
{
  const int m = blockIdx.x, t = threadIdx.x;
  const int h0 = t * 2;
  float2 kv = *(const float2*)&Km[(size_t)m*HID + h0];
  if (*train == 0){
    mem[(size_t)m*HID + h0]     = kv.x;
    mem[(size_t)m*HID + h0 + 1] = kv.y;
    return;
  }
  float2 av = *(const float2*)&qacc[(size_t)m*HID + h0];
  float v0 = av.x + kv.x, v1 = av.y + kv.y;
  __shared__ float red[256];
  red[t] = v0*v0 + v1*v1;
  __syncthreads();
  for (int s = 128; s > 0; s >>= 1){
    if (t < s) red[t] += red[t + s];
    __syncthreads();
  }
  float rinv = 1.f / fmaxf(sqrtf(red[0]), 1e-12f);
  mem[(size_t)m*HID + h0]     = v0 * rinv;
  mem[(size_t)m*HID + h0 + 1] = v1 * rinv;
}

// ============================ host ============================

extern "C" void kernel_launch(void* const* d_in, const int* in_sizes, int n_in,
                              void* d_out, int out_size, void* d_ws, size_t ws_size,
                              hipStream_t stream)
{
  const float* x   = (const float*)d_in[0];
  const float* Km  = (const float*)d_in[1];
  const float* W1  = (const float*)d_in[2];
  const float* b1  = (const float*)d_in[3];
  const float* W2  = (const float*)d_in[4];
  const float* b2  = (const float*)d_in[5];
  const float* W3  = (const float*)d_in[6];
  const float* b3  = (const float*)d_in[7];
  const float* Wd  = (const float*)d_in[8];
  const float* bd  = (const float*)d_in[9];
  const int* train = (const int*)d_in[10];

  float* out  = (float*)d_out;
  float* pred = out;
  float* outN = out + 16384;
  float* outP = out + 16384 + 8388608;
  float* memo = out + 16384 + 2*8388608;

  char* ws = (char*)d_ws;
  unsigned short* Qhi   = (unsigned short*)(ws + 0);           // 16,777,216
  unsigned short* Qlo   = (unsigned short*)(ws + 16777216);    // 16,777,216
  // R0 region (aliased: xpad/h1/h2 all dead before Sb is written)
  unsigned short* xph   = (unsigned short*)(ws + 33554432);    // 12,582,912
  unsigned short* xpl   = (unsigned short*)(ws + 46137344);    // 12,582,912
  unsigned short* h1h   = (unsigned short*)(ws + 58720256);    // 16,777,216
  unsigned short* h1l   = (unsigned short*)(ws + 75497472);    // 16,777,216
  unsigned short* h2h   = (unsigned short*)(ws + 92274688);    // 16,777,216
  unsigned short* h2l   = (unsigned short*)(ws + 109051904);   // 16,777,216 (R0 end 125,829,120)
  unsigned short* Sb    = (unsigned short*)(ws + 33554432);    // 67,108,864 (aliases R0)
  unsigned short* Khi   = (unsigned short*)(ws + 125829120);   //  2,097,152
  unsigned short* Klo   = (unsigned short*)(ws + 127926272);   //  2,097,152
  unsigned short* Kt    = (unsigned short*)(ws + 130023424);   //  2,097,152
  unsigned short* W1ph  = (unsigned short*)(ws + 132120576);   //    393,216
  unsigned short* W1pl  = (unsigned short*)(ws + 132513792);   //    393,216
  unsigned short* W2h   = (unsigned short*)(ws + 132907008);   //    524,288
  unsigned short* W2l   = (unsigned short*)(ws + 133431296);   //    524,288
  unsigned short* W3h   = (unsigned short*)(ws + 133955584);   //    524,288
  unsigned short* W3l   = (unsigned short*)(ws + 134479872);   //    524,288
  float* pmax    = (float*)(ws + 135004160);                   //  2,097,152
  int*   pcol    = (int*)  (ws + 137101312);                   //  2,097,152
  float* psum    = (float*)(ws + 139198464);                   //  2,097,152
  float* pnmax   = (float*)(ws + 141295616);                   //  2,097,152
  float* pnsum   = (float*)(ws + 143392768);                   //  2,097,152
  float* pcolmax = (float*)(ws + 145489920);                   //  4,194,304 (512 rows)
  float* rowm    = (float*)(ws + 149684224);
  float* rsp     = (float*)(ws + 149749760);
  float* rmn     = (float*)(ws + 149815296);
  float* rsn     = (float*)(ws + 149880832);
  int*   gidx    = (int*)  (ws + 149946368);
  float* colmax  = (float*)(ws + 150011904);
  int*   cnt     = (int*)  (ws + 150020096);                   //      8,192
  int*   off     = (int*)  (ws + 150028288);                   //      8,448 (2049 ints)
  int*   woff    = (int*)  (ws + 150036736);                   //      8,192
  int*   rows    = (int*)  (ws + 150044928);                   //     65,536
  float* wv      = (float*)(ws + 150110464);                   //     65,536
  int*   sid     = (int*)  (ws + 150176000);                   //     65,536
  float* qacc    = (float*)(ws + 150241536);                   //  4,194,304
  const size_t NEED = 154435840ull;
  if (ws_size < NEED) return;  // harness provides >= 155 MB (proven round 2)

  dim3 blk(256);
  // conversions
  cvt_pad_split<<<(N_ROWS*KP1/4 + 255)/256, blk, 0, stream>>>(x,  xph,  xpl,  N_ROWS, D_INN, KP1);
  cvt_pad_split<<<(HID*KP1/4 + 255)/256,    blk, 0, stream>>>(W1, W1ph, W1pl, HID,    D_INN, KP1);
  cvt_split<<<HID*HID/2048,     blk, 0, stream>>>(W2, W2h, W2l, HID*HID);
  cvt_split<<<HID*HID/2048,     blk, 0, stream>>>(W3, W3h, W3l, HID*HID);
  cvt_split<<<M_SLOTS*HID/2048, blk, 0, stream>>>(Km, Khi, Klo, M_SLOTS*HID);
  kt_kernel<<<dim3(32, 8), blk, 0, stream>>>(Km, Kt);

  // MLP (split-bf16 MFMA); layer 3 fuses the pred dot (pred pre-init'd to bd)
  mlp_gemm<<<dim3(N_ROWS/64, 4), blk, 0, stream>>>(xph, xpl, W1ph, W1pl, b1, h1h, h1l, KP1,
                                                   (const float*)nullptr, (float*)nullptr);
  mlp_gemm<<<dim3(N_ROWS/64, 4), blk, 0, stream>>>(h1h, h1l, W2h, W2l, b2, h2h, h2l, HID,
                                                   (const float*)nullptr, (float*)nullptr);
  pred_init<<<N_ROWS/256, blk, 0, stream>>>(pred, bd);
  mlp_gemm<<<dim3(N_ROWS/64, 4), blk, 0, stream>>>(h2h, h2l, W3h, W3l, b3, Qhi, Qlo, HID,
                                                   Wd, pred);

  // attention stats + PV
  sgemm_stats<<<dim3(16, 256), blk, 0, stream>>>(Qhi, Qlo, Khi, Klo, Sb,
                                                 pmax, pcol, psum, pnmax, pnsum, pcolmax);
  hipMemsetAsync(cnt, 0, M_SLOTS*sizeof(int), stream);
  merge_rows<<<64, blk, 0, stream>>>(pmax, pcol, psum, pnmax, pnsum, rowm, rsp, rmn, rsn, gidx, cnt);
  merge_cols<<<8, blk, 0, stream>>>(pcolmax, colmax);
  pv2<<<dim3(2, 512), blk, 0, stream>>>(Sb, Kt, rowm, rsp, rmn, rsn, Qhi, Qlo, outP, outN);

  // upload via CSR + bounded scatter
  hipMemsetAsync(qacc, 0, M_SLOTS*HID*sizeof(float), stream);
  csr_scan<<<1, blk, 0, stream>>>(cnt, off, woff);
  csr_fill<<<N_ROWS/256, blk, 0, stream>>>(gidx, rowm, colmax, woff, rows, wv, sid);
  upload_scatter<<<N_ROWS/64, blk, 0, stream>>>(Qhi, Qlo, sid, rows, wv, train, qacc);
  upload_finish<<<M_SLOTS, blk, 0, stream>>>(qacc, Km, train, memo);
}